// Round 1
// baseline (310.528 us; speedup 1.0000x reference)
//
#include <hip/hip_runtime.h>

#define LAG 5
#define HID 256
#define NA 30
#define NE 870
#define TM 195
#define TT 200
#define NB 2
#define EPN 29
#define TB3 65                 // 195/3 time-tiles of 3
#define NROWS (NB * TM * NA)   // 11700 (b,t,n) rows
#define APAD 4
#define KC 32                  // K-chunk (1 MFMA k-step)
#define UVB 1463               // ceil(11700/8) u,v blocks in k1
#define W2F_ELEMS (HID * HID)  // 65536
#define W1F_ELEMS (HID * 288)  // 73728
#define NTILES (NB * NA * TB3) // 3900
#define K2GRID 256             // persistent: 1 block/CU
#define AROW (HID + APAD)      // 260 halves per A row
#define ABUF (96 * AROW)       // halves per A buffer (49,920 B)
#define K2_LDS_BYTES (2 * ABUF * 2 + 2 * 32 * 4)   // 100,096 B

typedef _Float16 f16;
typedef _Float16 f16x8 __attribute__((ext_vector_type(8)));
typedef float floatx4 __attribute__((ext_vector_type(4)));

// ---------------------------------------------------------------- K1: prep (f16 everywhere)
// [0,1463): u,v (8 rows/block) ; then W2 frag ; Wout1 frag ; Wout2 frag.
// Fragment order: chunk = col/16 ; element offset = ((chunk*KCHUNKS + kc)*64 + lane)*8.
// Lane holds B[col = chunk*16+(lane&15)][k = kc*32+(lane>>4)*8 .. +8] -> coalesced 16B/lane.
__global__ __launch_bounds__(256) void k1_prep(
    const float* __restrict__ inputs, const float* __restrict__ w_msg1,
    const float* __restrict__ b_msg1, const float* __restrict__ w_msg2,
    const float* __restrict__ w_out1, const float* __restrict__ w_out2,
    f16* __restrict__ u, f16* __restrict__ v, f16* __restrict__ w2frag,
    f16* __restrict__ w1frag, f16* __restrict__ w2ofrag)
{
    const int bid = blockIdx.x, tid = threadIdx.x;
    if (bid < UVB) {
        __shared__ float feats8[8][LAG];
        const int r0 = bid * 8;
        if (tid < 8 * LAG) {
            const int i = tid / LAG, l = tid % LAG;
            const int r = r0 + i;
            float fv = 0.f;
            if (r < NROWS) {
                const int b = r / (TM * NA), rem = r % (TM * NA);
                const int t = rem / NA, n = rem % NA;
                fv = inputs[(b * NA + n) * TT + t + l];
            }
            feats8[i][l] = fv;
        }
        float w1c[2 * LAG];
        #pragma unroll
        for (int k = 0; k < 2 * LAG; ++k) w1c[k] = w_msg1[k * HID + tid];
        const float bb = b_msg1[tid];
        __syncthreads();
        #pragma unroll
        for (int i = 0; i < 8; ++i) {
            const int r = r0 + i;
            if (r < NROWS) {
                float ua = bb, va = 0.f;
                #pragma unroll
                for (int l = 0; l < LAG; ++l) {
                    ua = fmaf(feats8[i][l], w1c[l], ua);
                    va = fmaf(feats8[i][l], w1c[LAG + l], va);
                }
                u[(r << 8) + tid] = (f16)ua;
                v[(r << 8) + tid] = (f16)va;
            }
        }
    } else if (bid < UVB + 32) {                      // W2^T frag (8 k-chunks)
        const int fidx = (bid - UVB) * 256 + tid;     // [0, 8192)
        const int lane = fidx & 63;
        const int kc = (fidx >> 6) & 7;
        const int ntc = fidx >> 9;                    // chunk = col/16
        const int col = ntc * 16 + (lane & 15);
        const int kb = kc * KC + (lane >> 4) * 8;
        f16x8 vv;
        #pragma unroll
        for (int x = 0; x < 8; ++x) vv[x] = (f16)w_msg2[(kb + x) * HID + col];
        *(f16x8*)&w2frag[fidx * 8] = vv;
    } else if (bid < UVB + 32 + 36) {                 // W_out1' frag (9 k-chunks, K=288)
        const int fidx = (bid - (UVB + 32)) * 256 + tid;  // [0, 9216)
        const int lane = fidx & 63;
        const int kc = (fidx >> 6) % 9;
        const int ntc = fidx / (64 * 9);
        const int col = ntc * 16 + (lane & 15);
        const int kb = kc * KC + (lane >> 4) * 8;
        f16x8 vv;
        #pragma unroll
        for (int x = 0; x < 8; ++x) {
            const int k = kb + x;
            float val;
            if (k < 256)      val = w_out1[(5 + k) * HID + col];   // agg part (rows 5..260)
            else if (k < 261) val = w_out1[(k - 256) * HID + col]; // feat part (rows 0..4)
            else              val = 0.f;                           // K-pad
            vv[x] = (f16)val;
        }
        *(f16x8*)&w1frag[fidx * 8] = vv;
    } else {                                          // W_out2^T frag (8 k-chunks)
        const int fidx = (bid - (UVB + 32 + 36)) * 256 + tid;
        const int lane = fidx & 63;
        const int kc = (fidx >> 6) & 7;
        const int ntc = fidx >> 9;
        const int col = ntc * 16 + (lane & 15);
        const int kb = kc * KC + (lane >> 4) * 8;
        f16x8 vv;
        #pragma unroll
        for (int x = 0; x < 8; ++x) vv[x] = (f16)w_msg2[0] * (f16)0.f + (f16)w_out2[(kb + x) * HID + col];
        *(f16x8*)&w2ofrag[fidx * 8] = vv;
    }
}

// ---------------------------------------------------------------- K2: msg MLP + edge-weighted aggregation
// PERSISTENT version: 256 blocks (1/CU, 8 waves), each owns ~15 tiles.
//  - full W2 slice per wave held in 64 VGPRs (loaded once -> no B traffic in loop)
//  - A double-buffered in LDS (2 x 49.9 KB dynamic); u/v loads for tile i+1 issued
//    right after the barrier, land under tile i's GEMM, ds_write'd after (T14)
//  - one barrier per tile; setprio(1) around the MFMA cluster (T5)
__global__ __launch_bounds__(512, 2) void k2_msg(
    const f16* __restrict__ u, const f16* __restrict__ v,
    const f16* __restrict__ w2frag,
    const float* __restrict__ mu, const float* __restrict__ logvar,
    const float* __restrict__ eps, const float* __restrict__ b_msg2,
    f16* __restrict__ agg)
{
    extern __shared__ f16 smem[];                 // [2][96][AROW] + ev[2][32]
    float* evb = (float*)(smem + 2 * ABUF);

    const int tid = threadIdx.x;
    const int lane = tid & 63, w = tid >> 6;      // w in [0,8)
    const int q = lane >> 4, m15 = lane & 15;
    const int wbase = w * 32;                     // 32-col slice per wave
    const int tid5 = tid >> 5;                    // 0..15 : staging row-within-16
    const int cc = (tid & 31) * 8;                // staging chunk offset (halves)

    // ---- B: full W2 slice in registers, loaded once per block ----
    f16x8 bfr[2][8];
    #pragma unroll
    for (int nt = 0; nt < 2; ++nt)
        #pragma unroll
        for (int kc = 0; kc < 8; ++kc)
            bfr[nt][kc] = *(const f16x8*)(w2frag + ((((w * 2 + nt) * 8 + kc) << 9) + (lane << 3)));

    float b2v[2];
    #pragma unroll
    for (int nt = 0; nt < 2; ++nt) b2v[nt] = b_msg2[wbase + nt * 16 + m15];

    const f16x8 z8 = {(f16)0, (f16)0, (f16)0, (f16)0, (f16)0, (f16)0, (f16)0, (f16)0};

    // current tile state
    int tile = blockIdx.x;
    int cn = tile % NA;
    int cr = tile / NA;
    int ct0 = (cr % TB3) * 3, cb = cr / TB3;

    f16x8 su[6], sv[3];
    float r_eps = 0.f, r_lv = 0.f, r_mu = 0.f;

    // ---- prologue: load + write tile0 into buf 0 ----
    {
        const int sbase = (cb * TM + ct0) * NA;
        const int j_e = tid5 + (tid5 >= cn);
        const int j_o = 16 + tid5 + ((16 + tid5) >= cn);
        #pragma unroll
        for (int i = 0; i < 6; ++i) {
            const int ttt = i >> 1;
            if (!(i & 1))
                su[i] = *(const f16x8*)(u + (((sbase + ttt * NA + j_e) << 8) + cc));
            else if (tid5 < 13)   // odd i: edge index 16+tid5, valid when < 29
                su[i] = *(const f16x8*)(u + (((sbase + ttt * NA + j_o) << 8) + cc));
        }
        #pragma unroll
        for (int ttt = 0; ttt < 3; ++ttt)
            sv[ttt] = *(const f16x8*)(v + (((sbase + ttt * NA + cn) << 8) + cc));
        if (tid < EPN) {
            const int e = cb * NE + cn * EPN + tid;
            r_eps = eps[e]; r_lv = logvar[e]; r_mu = mu[e];
        }
        #pragma unroll
        for (int i = 0; i < 6; ++i) {
            f16x8 out8 = z8;
            if (!(i & 1) || tid5 < 13)
                out8 = __builtin_elementwise_max(su[i] + sv[i >> 1], z8);
            *(f16x8*)(smem + (i * 16 + tid5) * AROW + cc) = out8;
        }
        if (tid < 32) {
            float evv = 0.f;
            if (tid < EPN) evv = r_eps * __expf(0.5f * r_lv) + r_mu;
            evb[tid] = evv;
        }
    }

    int cur = 0;
    for (;;) {
        const int nxt = tile + K2GRID;
        const bool have = (nxt < NTILES);
        int nn = 0, nt0 = 0, nb = 0;

        __syncthreads();   // buf[cur]+ev[cur] staged; all reads of buf[cur^1] done

        if (have) {        // issue next tile's loads -> land under this GEMM
            nn = nxt % NA;
            const int nr = nxt / NA;
            nt0 = (nr % TB3) * 3; nb = nr / TB3;
            const int sbase = (nb * TM + nt0) * NA;
            const int j_e = tid5 + (tid5 >= nn);
            const int j_o = 16 + tid5 + ((16 + tid5) >= nn);
            #pragma unroll
            for (int i = 0; i < 6; ++i) {
                const int ttt = i >> 1;
                if (!(i & 1))
                    su[i] = *(const f16x8*)(u + (((sbase + ttt * NA + j_e) << 8) + cc));
                else if (tid5 < 13)
                    su[i] = *(const f16x8*)(u + (((sbase + ttt * NA + j_o) << 8) + cc));
            }
            #pragma unroll
            for (int ttt = 0; ttt < 3; ++ttt)
                sv[ttt] = *(const f16x8*)(v + (((sbase + ttt * NA + nn) << 8) + cc));
            if (tid < EPN) {
                const int e = nb * NE + nn * EPN + tid;
                r_eps = eps[e]; r_lv = logvar[e]; r_mu = mu[e];
            }
        }

        // ---- GEMM on buf[cur]: pure ds_read + MFMA (B in regs) ----
        floatx4 acc[6][2];
        #pragma unroll
        for (int mt = 0; mt < 6; ++mt)
            #pragma unroll
            for (int nt = 0; nt < 2; ++nt)
                acc[mt][nt] = (floatx4){0.f, 0.f, 0.f, 0.f};

        const f16* abuf = smem + cur * ABUF;
        __builtin_amdgcn_s_setprio(1);
        #pragma unroll
        for (int kc = 0; kc < 8; ++kc) {
            f16x8 af[6];
            #pragma unroll
            for (int mt = 0; mt < 6; ++mt)
                af[mt] = *(const f16x8*)(abuf + (mt * 16 + m15) * AROW + kc * KC + q * 8);
            #pragma unroll
            for (int nt = 0; nt < 2; ++nt)
                #pragma unroll
                for (int mt = 0; mt < 6; ++mt)
                    acc[mt][nt] = __builtin_amdgcn_mfma_f32_16x16x32_f16(af[mt], bfr[nt][kc], acc[mt][nt], 0, 0, 0);
        }
        __builtin_amdgcn_s_setprio(0);

        // ---- write next tile into buf[cur^1] (loads have landed under GEMM) ----
        if (have) {
            f16* nbuf = smem + (cur ^ 1) * ABUF;
            #pragma unroll
            for (int i = 0; i < 6; ++i) {
                f16x8 out8 = z8;
                if (!(i & 1) || tid5 < 13)
                    out8 = __builtin_elementwise_max(su[i] + sv[i >> 1], z8);
                *(f16x8*)(nbuf + (i * 16 + tid5) * AROW + cc) = out8;
            }
            if (tid < 32) {
                float evv = 0.f;
                if (tid < EPN) evv = r_eps * __expf(0.5f * r_lv) + r_mu;
                evb[(cur ^ 1) * 32 + tid] = evv;
            }
        }

        // ---- epilogue: msg = relu(acc + b2) * edgeval ; sum edges -> agg[b,t,n,:] ----
        const float* ev = evb + cur * 32;
        #pragma unroll
        for (int tt = 0; tt < 3; ++tt) {
            const int t = ct0 + tt;
            #pragma unroll
            for (int nt = 0; nt < 2; ++nt) {
                float part = 0.f;
                #pragma unroll
                for (int ml = 0; ml < 2; ++ml) {
                    const int mt = tt * 2 + ml;
                    #pragma unroll
                    for (int reg = 0; reg < 4; ++reg) {
                        const int ei = ml * 16 + q * 4 + reg;    // C-layout row = q*4+reg
                        part += ev[ei] * fmaxf(acc[mt][nt][reg] + b2v[nt], 0.f);
                    }
                }
                part += __shfl_xor(part, 16, 64);
                part += __shfl_xor(part, 32, 64);
                if (q == 0)
                    agg[((((cb * TM + t) * NA + cn) << 8) + wbase + nt * 16 + m15)] = (f16)part;
            }
        }

        if (!have) break;
        tile = nxt; cn = nn; ct0 = nt0; cb = nb; cur ^= 1;
    }
}

// ---------------------------------------------------------------- K3: out MLP 288->256->256->1 (f16)
// block per 16 rows (732 blocks). B from frag-order global, double-buffered.
__global__ __launch_bounds__(256) void k3_out(
    const f16* __restrict__ agg, const float* __restrict__ inputs,
    const f16* __restrict__ w1frag, const f16* __restrict__ w2ofrag,
    const float* __restrict__ b_out1, const float* __restrict__ b_out2,
    const float* __restrict__ w_out3, const float* __restrict__ b_out3,
    float* __restrict__ out)
{
    __shared__ f16 a1[16][288 + APAD];
    __shared__ float red[4][16];

    const int R0 = blockIdx.x * 16;
    const int tid = threadIdx.x;
    const int lane = tid & 63, w = tid >> 6;
    const int q = lane >> 4, m15 = lane & 15;
    const int wbase = w * 64;

    // ---- stage A1 = [agg(256) | feat(5) | 0...] ----
    #pragma unroll
    for (int i = 0; i < 2; ++i) {
        const int task = i * 256 + tid;                // [0,512): 16 rows x 32 chunks
        const int row = task >> 5, c = task & 31;
        const int R = R0 + row;
        f16x8 val;
        if (R < NROWS) {
            val = *(const f16x8*)&agg[(R << 8) + c * 8];
        } else {
            for (int x = 0; x < 8; ++x) val[x] = (f16)0.f;
        }
        *(f16x8*)&a1[row][c * 8] = val;
    }
    if (tid < 16) {
        const int R = R0 + tid;
        if (R < NROWS) {
            const int b = R / (TM * NA), rem = R % (TM * NA);
            const int t = rem / NA, n = rem % NA;
            const float* ip = inputs + (b * NA + n) * TT + t;
            #pragma unroll
            for (int l = 0; l < LAG; ++l) a1[tid][256 + l] = (f16)ip[l];
            #pragma unroll
            for (int k = 261; k < 288; ++k) a1[tid][k] = (f16)0.f;
        } else {
            for (int k = 256; k < 288; ++k) a1[tid][k] = (f16)0.f;
        }
    }

    floatx4 acc[4];
    #pragma unroll
    for (int nt = 0; nt < 4; ++nt) acc[nt] = (floatx4){0.f, 0.f, 0.f, 0.f};

    // ---- GEMM1: K=288 (9 chunks) ----
    const f16* b1base = w1frag + (lane << 3);
    f16x8 bcur[4], bnxt[4];
    #pragma unroll
    for (int nt = 0; nt < 4; ++nt)
        bcur[nt] = *(const f16x8*)(b1base + (((w * 4 + nt) * 9 + 0) << 9));

    __syncthreads();   // A1 staged

    #pragma unroll
    for (int kc = 0; kc < 9; ++kc) {
        if (kc < 8) {
            #pragma unroll
            for (int nt = 0; nt < 4; ++nt)
                bnxt[nt] = *(const f16x8*)(b1base + (((w * 4 + nt) * 9 + kc + 1) << 9));
        }
        const f16x8 af = *(const f16x8*)&a1[m15][kc * KC + q * 8];
        #pragma unroll
        for (int nt = 0; nt < 4; ++nt)
            acc[nt] = __builtin_amdgcn_mfma_f32_16x16x32_f16(af, bcur[nt], acc[nt], 0, 0, 0);
        #pragma unroll
        for (int nt = 0; nt < 4; ++nt) bcur[nt] = bnxt[nt];
    }
    __syncthreads();   // all GEMM1 reads of a1 done before overwrite

    // ---- epilogue1: out1 = relu(acc + b_out1) -> a1[:, 0:256] ----
    {
        float b1v[4];
        #pragma unroll
        for (int nt = 0; nt < 4; ++nt) b1v[nt] = b_out1[wbase + nt * 16 + m15];
        #pragma unroll
        for (int nt = 0; nt < 4; ++nt)
            #pragma unroll
            for (int reg = 0; reg < 4; ++reg)
                a1[q * 4 + reg][wbase + nt * 16 + m15] =
                    (f16)fmaxf(acc[nt][reg] + b1v[nt], 0.f);
    }

    #pragma unroll
    for (int nt = 0; nt < 4; ++nt) acc[nt] = (floatx4){0.f, 0.f, 0.f, 0.f};

    // ---- GEMM2: K=256 (8 chunks) ----
    const f16* b2base = w2ofrag + (lane << 3);
    #pragma unroll
    for (int nt = 0; nt < 4; ++nt)
        bcur[nt] = *(const f16x8*)(b2base + (((w * 4 + nt) * 8 + 0) << 9));

    __syncthreads();   // epilogue1 writes visible

    #pragma unroll
    for (int kc = 0; kc < 8; ++kc) {
        if (kc < 7) {
            #pragma unroll
            for (int nt = 0; nt < 4; ++nt)
                bnxt[nt] = *(const f16x8*)(b2base + (((w * 4 + nt) * 8 + kc + 1) << 9));
        }
        const f16x8 af = *(const f16x8*)&a1[m15][kc * KC + q * 8];
        #pragma unroll
        for (int nt = 0; nt < 4; ++nt)
            acc[nt] = __builtin_amdgcn_mfma_f32_16x16x32_f16(af, bcur[nt], acc[nt], 0, 0, 0);
        #pragma unroll
        for (int nt = 0; nt < 4; ++nt) bcur[nt] = bnxt[nt];
    }

    // ---- epilogue2: relu(+b_out2), dot w_out3, reduce over 256 cols ----
    {
        float b2v[4], w3v[4];
        #pragma unroll
        for (int nt = 0; nt < 4; ++nt) {
            const int col = wbase + nt * 16 + m15;
            b2v[nt] = b_out2[col];
            w3v[nt] = w_out3[col];
        }
        #pragma unroll
        for (int reg = 0; reg < 4; ++reg) {
            float p = 0.f;
            #pragma unroll
            for (int nt = 0; nt < 4; ++nt)
                p += fmaxf(acc[nt][reg] + b2v[nt], 0.f) * w3v[nt];
            p += __shfl_xor(p, 1, 64);
            p += __shfl_xor(p, 2, 64);
            p += __shfl_xor(p, 4, 64);
            p += __shfl_xor(p, 8, 64);
            if (m15 == 0) red[w][q * 4 + reg] = p;
        }
    }
    __syncthreads();
    if (tid < 16) {
        const int R = R0 + tid;
        if (R < NROWS) {
            const float val = red[0][tid] + red[1][tid] + red[2][tid] + red[3][tid] + b_out3[0];
            const int b = R / (TM * NA), rem = R % (TM * NA);
            const int t = rem / NA, n = rem % NA;
            out[(b * NA + n) * TM + t] = val;
        }
    }
}

// ----------------------------------------------------------------
extern "C" void kernel_launch(void* const* d_in, const int* in_sizes, int n_in,
                              void* d_out, int out_size, void* d_ws, size_t ws_size,
                              hipStream_t stream) {
    const float* inputs  = (const float*)d_in[0];
    const float* mu      = (const float*)d_in[1];
    const float* logvar  = (const float*)d_in[2];
    const float* eps     = (const float*)d_in[3];
    const float* w_msg1  = (const float*)d_in[6];
    const float* b_msg1  = (const float*)d_in[7];
    const float* w_msg2  = (const float*)d_in[8];
    const float* b_msg2  = (const float*)d_in[9];
    const float* w_out1  = (const float*)d_in[10];
    const float* b_out1  = (const float*)d_in[11];
    const float* w_out2  = (const float*)d_in[12];
    const float* b_out2  = (const float*)d_in[13];
    const float* w_out3  = (const float*)d_in[14];
    const float* b_out3  = (const float*)d_in[15];
    float* out = (float*)d_out;

    // workspace (f16 elems): u, v, agg (11700*256 each); frag-order W2, Wout1, Wout2
    f16* u       = (f16*)d_ws;
    f16* v       = u       + NROWS * HID;
    f16* aggw    = v       + NROWS * HID;
    f16* w2frag  = aggw    + NROWS * HID;
    f16* w1frag  = w2frag  + W2F_ELEMS;
    f16* w2ofrag = w1frag  + W1F_ELEMS;   // total ~18.4 MB

    static int k2_attr_done = 0;
    if (!k2_attr_done) {
        hipFuncSetAttribute(reinterpret_cast<const void*>(k2_msg),
                            hipFuncAttributeMaxDynamicSharedMemorySize,
                            (int)K2_LDS_BYTES);
        k2_attr_done = 1;
    }

    hipLaunchKernelGGL(k1_prep, dim3(UVB + 32 + 36 + 32), dim3(256), 0, stream,
                       inputs, w_msg1, b_msg1, w_msg2, w_out1, w_out2,
                       u, v, w2frag, w1frag, w2ofrag);
    hipLaunchKernelGGL(k2_msg, dim3(K2GRID), dim3(512), K2_LDS_BYTES, stream,
                       u, v, w2frag, mu, logvar, eps, b_msg2, aggw);
    hipLaunchKernelGGL(k3_out, dim3((NROWS + 15) / 16), dim3(256), 0, stream,
                       aggw, inputs, w1frag, w2ofrag, b_out1, b_out2, w_out3, b_out3, out);
}

// Round 2
// 162.810 us; speedup vs baseline: 1.9073x; 1.9073x over previous
//
#include <hip/hip_runtime.h>

#define LAG 5
#define HID 256
#define NA 30
#define NE 870
#define TM 195
#define TT 200
#define NB 2
#define EPN 29
#define TB3 65                 // 195/3 time-tiles of 3
#define NROWS (NB * TM * NA)   // 11700 (b,t,n) rows
#define APAD 4
#define KC 32                  // K-chunk for 16x16 frags (k3)
#define UVB 1463               // ceil(11700/8) u,v blocks in k1
#define W2F_ELEMS (HID * HID)  // 65536
#define W1F_ELEMS (HID * 288)  // 73728

typedef _Float16 f16;
typedef _Float16 f16x8 __attribute__((ext_vector_type(8)));
typedef float floatx4 __attribute__((ext_vector_type(4)));
typedef float floatx16 __attribute__((ext_vector_type(16)));

// ---------------------------------------------------------------- K1: prep (f16 everywhere)
// [0,1463): u,v (8 rows/block) ; then W2 frag (32x32 order) ; Wout1 frag ; Wout2 frag.
// 16x16 frag order (k3): chunk = col/16 ; offset = ((chunk*KCHUNKS + kc)*64 + lane)*8,
//   lane holds B[col = chunk*16+(lane&15)][k = kc*32+(lane>>4)*8 .. +8].
// 32x32 frag order (k2): chunk = col/32 ; offset = ((chunk*16 + kc)*64 + lane)*8,
//   lane holds B[col = chunk*32+(lane&31)][k = kc*16+(lane>>5)*8 .. +8].
__global__ __launch_bounds__(256) void k1_prep(
    const float* __restrict__ inputs, const float* __restrict__ w_msg1,
    const float* __restrict__ b_msg1, const float* __restrict__ w_msg2,
    const float* __restrict__ w_out1, const float* __restrict__ w_out2,
    f16* __restrict__ u, f16* __restrict__ v, f16* __restrict__ w2frag,
    f16* __restrict__ w1frag, f16* __restrict__ w2ofrag)
{
    const int bid = blockIdx.x, tid = threadIdx.x;
    if (bid < UVB) {
        __shared__ float feats8[8][LAG];
        const int r0 = bid * 8;
        if (tid < 8 * LAG) {
            const int i = tid / LAG, l = tid % LAG;
            const int r = r0 + i;
            float fv = 0.f;
            if (r < NROWS) {
                const int b = r / (TM * NA), rem = r % (TM * NA);
                const int t = rem / NA, n = rem % NA;
                fv = inputs[(b * NA + n) * TT + t + l];
            }
            feats8[i][l] = fv;
        }
        float w1c[2 * LAG];
        #pragma unroll
        for (int k = 0; k < 2 * LAG; ++k) w1c[k] = w_msg1[k * HID + tid];
        const float bb = b_msg1[tid];
        __syncthreads();
        #pragma unroll
        for (int i = 0; i < 8; ++i) {
            const int r = r0 + i;
            if (r < NROWS) {
                float ua = bb, va = 0.f;
                #pragma unroll
                for (int l = 0; l < LAG; ++l) {
                    ua = fmaf(feats8[i][l], w1c[l], ua);
                    va = fmaf(feats8[i][l], w1c[LAG + l], va);
                }
                u[(r << 8) + tid] = (f16)ua;
                v[(r << 8) + tid] = (f16)va;
            }
        }
    } else if (bid < UVB + 32) {                      // W2^T frag, 32x32 order (16 k-chunks of 16)
        const int fidx = (bid - UVB) * 256 + tid;     // [0, 8192)
        const int lane = fidx & 63;
        const int kc = (fidx >> 6) & 15;
        const int c32 = fidx >> 10;                   // chunk = col/32
        const int col = c32 * 32 + (lane & 31);
        const int kb = kc * 16 + (lane >> 5) * 8;
        f16x8 vv;
        #pragma unroll
        for (int x = 0; x < 8; ++x) vv[x] = (f16)w_msg2[(kb + x) * HID + col];
        *(f16x8*)&w2frag[fidx * 8] = vv;
    } else if (bid < UVB + 32 + 36) {                 // W_out1' frag (9 k-chunks, K=288), 16x16 order
        const int fidx = (bid - (UVB + 32)) * 256 + tid;  // [0, 9216)
        const int lane = fidx & 63;
        const int kc = (fidx >> 6) % 9;
        const int ntc = fidx / (64 * 9);
        const int col = ntc * 16 + (lane & 15);
        const int kb = kc * KC + (lane >> 4) * 8;
        f16x8 vv;
        #pragma unroll
        for (int x = 0; x < 8; ++x) {
            const int k = kb + x;
            float val;
            if (k < 256)      val = w_out1[(5 + k) * HID + col];   // agg part (rows 5..260)
            else if (k < 261) val = w_out1[(k - 256) * HID + col]; // feat part (rows 0..4)
            else              val = 0.f;                           // K-pad
            vv[x] = (f16)val;
        }
        *(f16x8*)&w1frag[fidx * 8] = vv;
    } else {                                          // W_out2^T frag (8 k-chunks), 16x16 order
        const int fidx = (bid - (UVB + 32 + 36)) * 256 + tid;
        const int lane = fidx & 63;
        const int kc = (fidx >> 6) & 7;
        const int ntc = fidx >> 9;
        const int col = ntc * 16 + (lane & 15);
        const int kb = kc * KC + (lane >> 4) * 8;
        f16x8 vv;
        #pragma unroll
        for (int x = 0; x < 8; ++x) vv[x] = (f16)w_out2[(kb + x) * HID + col];
        *(f16x8*)&w2ofrag[fidx * 8] = vv;
    }
}

// ---------------------------------------------------------------- K2: msg MLP + edge-weighted aggregation
// 256 threads / 4 waves; block per (b, n, t-tile of 3). M=96 (3t x 32 edge-slots), N=256, K=256.
// 32x32x16 MFMA; wave owns 64 cols (2 c32 chunks). A in XOR-swizzled LDS (512B rows, 16B-aligned,
// 2-way-free ds_read_b128). B streamed 2-deep from frag-order global. One barrier.
__global__ __launch_bounds__(256, 3) void k2_msg(
    const f16* __restrict__ u, const f16* __restrict__ v,
    const f16* __restrict__ w2frag,
    const float* __restrict__ mu, const float* __restrict__ logvar,
    const float* __restrict__ eps, const float* __restrict__ b_msg2,
    f16* __restrict__ agg)
{
    __shared__ f16 a_lds[96 * 256];     // 49,152 B, swizzled: half_off ^= (row&7)<<3
    __shared__ float ev_lds[32];

    const int bid = blockIdx.x;
    const int n  = bid % NA;
    const int tb = (bid / NA) % TB3;
    const int b  = bid / (NA * TB3);
    const int t0 = tb * 3;
    const int tid = threadIdx.x;
    const int lane = tid & 63, w = tid >> 6;   // w in [0,4)
    const int h = lane >> 5, l31 = lane & 31;

    if (tid < 32) {
        float evv = 0.f;
        if (tid < EPN) {
            const int e = b * NE + n * EPN + tid;
            evv = eps[e] * __expf(0.5f * logvar[e]) + mu[e];
        }
        ev_lds[tid] = evv;
    }

    const f16x8 z8 = {(f16)0, (f16)0, (f16)0, (f16)0, (f16)0, (f16)0, (f16)0, (f16)0};

    // ---- stage A = relu(u[send] + v[recv]) : 96 rows x 32 chunks = 3072 tasks ----
    const int sbase = (b * TM + t0) * NA;
    #pragma unroll
    for (int i = 0; i < 12; ++i) {
        const int task = i * 256 + tid;
        const int row = task >> 5, c = task & 31;
        const int tt = row >> 5, ei = row & 31;
        f16x8 out8 = z8;
        if (ei < EPN) {
            const int j = ei + (ei >= n);
            const f16x8 uu = *(const f16x8*)(u + (((sbase + tt * NA + j) << 8) + c * 8));
            const f16x8 vv = *(const f16x8*)(v + (((sbase + tt * NA + n) << 8) + c * 8));
            out8 = __builtin_elementwise_max(uu + vv, z8);   // v_pk_add_f16 + v_pk_max_f16
        }
        *(f16x8*)&a_lds[row * 256 + ((c * 8) ^ ((row & 7) << 3))] = out8;
    }

    // ---- B prefetch: frag offset = ((c32*16 + kc)*64 + lane)*8, c32 = w*2+nt ----
    const f16* bbase = w2frag + (lane << 3);
    f16x8 b0[2], b1[2], b2[2];
    #pragma unroll
    for (int nt = 0; nt < 2; ++nt) {
        const int c32 = w * 2 + nt;
        b0[nt] = *(const f16x8*)(bbase + (((c32 * 16) + 0) << 9));
        b1[nt] = *(const f16x8*)(bbase + (((c32 * 16) + 1) << 9));
    }

    floatx16 acc[3][2];
    #pragma unroll
    for (int mt = 0; mt < 3; ++mt)
        #pragma unroll
        for (int nt = 0; nt < 2; ++nt)
            #pragma unroll
            for (int x = 0; x < 16; ++x) acc[mt][nt][x] = 0.f;

    __syncthreads();   // A + ev staged (the only barrier)

    #pragma unroll
    for (int kc = 0; kc < 16; ++kc) {
        if (kc < 14) {
            #pragma unroll
            for (int nt = 0; nt < 2; ++nt)
                b2[nt] = *(const f16x8*)(bbase + ((((w * 2 + nt) * 16) + kc + 2) << 9));
        }
        f16x8 af[3];
        #pragma unroll
        for (int mt = 0; mt < 3; ++mt) {
            const int row = mt * 32 + l31;
            af[mt] = *(const f16x8*)&a_lds[row * 256 + ((kc * 16 + h * 8) ^ ((row & 7) << 3))];
        }
        #pragma unroll
        for (int nt = 0; nt < 2; ++nt)
            #pragma unroll
            for (int mt = 0; mt < 3; ++mt)
                acc[mt][nt] = __builtin_amdgcn_mfma_f32_32x32x16_f16(af[mt], b0[nt], acc[mt][nt], 0, 0, 0);
        #pragma unroll
        for (int nt = 0; nt < 2; ++nt) { b0[nt] = b1[nt]; b1[nt] = b2[nt]; }
    }

    // ---- epilogue: msg = relu(acc + b2) * edgeval ; sum edges -> agg[b,t,n,:] ----
    // C layout (32x32): col = lane&31 (+c32*32), row = (reg&3) + 8*(reg>>2) + 4*h
    float evr[16];
    #pragma unroll
    for (int reg = 0; reg < 16; ++reg)
        evr[reg] = ev_lds[(reg & 3) + 8 * (reg >> 2) + 4 * h];
    float b2s[2];
    #pragma unroll
    for (int nt = 0; nt < 2; ++nt) b2s[nt] = b_msg2[w * 64 + nt * 32 + l31];

    #pragma unroll
    for (int mt = 0; mt < 3; ++mt) {
        const int t = t0 + mt;
        #pragma unroll
        for (int nt = 0; nt < 2; ++nt) {
            float part = 0.f;
            #pragma unroll
            for (int reg = 0; reg < 16; ++reg)
                part += evr[reg] * fmaxf(acc[mt][nt][reg] + b2s[nt], 0.f);
            part += __shfl_xor(part, 32, 64);
            if (h == 0)
                agg[(((b * TM + t) * NA + n) << 8) + w * 64 + nt * 32 + l31] = (f16)part;
        }
    }
}

// ---------------------------------------------------------------- K3: out MLP 288->256->256->1 (f16)
// block per 16 rows (732 blocks). B from frag-order global, double-buffered.
__global__ __launch_bounds__(256) void k3_out(
    const f16* __restrict__ agg, const float* __restrict__ inputs,
    const f16* __restrict__ w1frag, const f16* __restrict__ w2ofrag,
    const float* __restrict__ b_out1, const float* __restrict__ b_out2,
    const float* __restrict__ w_out3, const float* __restrict__ b_out3,
    float* __restrict__ out)
{
    __shared__ f16 a1[16][288 + APAD];
    __shared__ float red[4][16];

    const int R0 = blockIdx.x * 16;
    const int tid = threadIdx.x;
    const int lane = tid & 63, w = tid >> 6;
    const int q = lane >> 4, m15 = lane & 15;
    const int wbase = w * 64;

    // ---- stage A1 = [agg(256) | feat(5) | 0...] ----
    #pragma unroll
    for (int i = 0; i < 2; ++i) {
        const int task = i * 256 + tid;                // [0,512): 16 rows x 32 chunks
        const int row = task >> 5, c = task & 31;
        const int R = R0 + row;
        f16x8 val;
        if (R < NROWS) {
            val = *(const f16x8*)&agg[(R << 8) + c * 8];
        } else {
            for (int x = 0; x < 8; ++x) val[x] = (f16)0.f;
        }
        *(f16x8*)&a1[row][c * 8] = val;
    }
    if (tid < 16) {
        const int R = R0 + tid;
        if (R < NROWS) {
            const int b = R / (TM * NA), rem = R % (TM * NA);
            const int t = rem / NA, n = rem % NA;
            const float* ip = inputs + (b * NA + n) * TT + t;
            #pragma unroll
            for (int l = 0; l < LAG; ++l) a1[tid][256 + l] = (f16)ip[l];
            #pragma unroll
            for (int k = 261; k < 288; ++k) a1[tid][k] = (f16)0.f;
        } else {
            for (int k = 256; k < 288; ++k) a1[tid][k] = (f16)0.f;
        }
    }

    floatx4 acc[4];
    #pragma unroll
    for (int nt = 0; nt < 4; ++nt) acc[nt] = (floatx4){0.f, 0.f, 0.f, 0.f};

    // ---- GEMM1: K=288 (9 chunks) ----
    const f16* b1base = w1frag + (lane << 3);
    f16x8 bcur[4], bnxt[4];
    #pragma unroll
    for (int nt = 0; nt < 4; ++nt)
        bcur[nt] = *(const f16x8*)(b1base + (((w * 4 + nt) * 9 + 0) << 9));

    __syncthreads();   // A1 staged

    #pragma unroll
    for (int kc = 0; kc < 9; ++kc) {
        if (kc < 8) {
            #pragma unroll
            for (int nt = 0; nt < 4; ++nt)
                bnxt[nt] = *(const f16x8*)(b1base + (((w * 4 + nt) * 9 + kc + 1) << 9));
        }
        const f16x8 af = *(const f16x8*)&a1[m15][kc * KC + q * 8];
        #pragma unroll
        for (int nt = 0; nt < 4; ++nt)
            acc[nt] = __builtin_amdgcn_mfma_f32_16x16x32_f16(af, bcur[nt], acc[nt], 0, 0, 0);
        #pragma unroll
        for (int nt = 0; nt < 4; ++nt) bcur[nt] = bnxt[nt];
    }
    __syncthreads();   // all GEMM1 reads of a1 done before overwrite

    // ---- epilogue1: out1 = relu(acc + b_out1) -> a1[:, 0:256] ----
    {
        float b1v[4];
        #pragma unroll
        for (int nt = 0; nt < 4; ++nt) b1v[nt] = b_out1[wbase + nt * 16 + m15];
        #pragma unroll
        for (int nt = 0; nt < 4; ++nt)
            #pragma unroll
            for (int reg = 0; reg < 4; ++reg)
                a1[q * 4 + reg][wbase + nt * 16 + m15] =
                    (f16)fmaxf(acc[nt][reg] + b1v[nt], 0.f);
    }

    #pragma unroll
    for (int nt = 0; nt < 4; ++nt) acc[nt] = (floatx4){0.f, 0.f, 0.f, 0.f};

    // ---- GEMM2: K=256 (8 chunks) ----
    const f16* b2base = w2ofrag + (lane << 3);
    #pragma unroll
    for (int nt = 0; nt < 4; ++nt)
        bcur[nt] = *(const f16x8*)(b2base + (((w * 4 + nt) * 8 + 0) << 9));

    __syncthreads();   // epilogue1 writes visible

    #pragma unroll
    for (int kc = 0; kc < 8; ++kc) {
        if (kc < 7) {
            #pragma unroll
            for (int nt = 0; nt < 4; ++nt)
                bnxt[nt] = *(const f16x8*)(b2base + (((w * 4 + nt) * 8 + kc + 1) << 9));
        }
        const f16x8 af = *(const f16x8*)&a1[m15][kc * KC + q * 8];
        #pragma unroll
        for (int nt = 0; nt < 4; ++nt)
            acc[nt] = __builtin_amdgcn_mfma_f32_16x16x32_f16(af, bcur[nt], acc[nt], 0, 0, 0);
        #pragma unroll
        for (int nt = 0; nt < 4; ++nt) bcur[nt] = bnxt[nt];
    }

    // ---- epilogue2: relu(+b_out2), dot w_out3, reduce over 256 cols ----
    {
        float b2v[4], w3v[4];
        #pragma unroll
        for (int nt = 0; nt < 4; ++nt) {
            const int col = wbase + nt * 16 + m15;
            b2v[nt] = b_out2[col];
            w3v[nt] = w_out3[col];
        }
        #pragma unroll
        for (int reg = 0; reg < 4; ++reg) {
            float p = 0.f;
            #pragma unroll
            for (int nt = 0; nt < 4; ++nt)
                p += fmaxf(acc[nt][reg] + b2v[nt], 0.f) * w3v[nt];
            p += __shfl_xor(p, 1, 64);
            p += __shfl_xor(p, 2, 64);
            p += __shfl_xor(p, 4, 64);
            p += __shfl_xor(p, 8, 64);
            if (m15 == 0) red[w][q * 4 + reg] = p;
        }
    }
    __syncthreads();
    if (tid < 16) {
        const int R = R0 + tid;
        if (R < NROWS) {
            const float val = red[0][tid] + red[1][tid] + red[2][tid] + red[3][tid] + b_out3[0];
            const int b = R / (TM * NA), rem = R % (TM * NA);
            const int t = rem / NA, n = rem % NA;
            out[(b * NA + n) * TM + t] = val;
        }
    }
}

// ----------------------------------------------------------------
extern "C" void kernel_launch(void* const* d_in, const int* in_sizes, int n_in,
                              void* d_out, int out_size, void* d_ws, size_t ws_size,
                              hipStream_t stream) {
    const float* inputs  = (const float*)d_in[0];
    const float* mu      = (const float*)d_in[1];
    const float* logvar  = (const float*)d_in[2];
    const float* eps     = (const float*)d_in[3];
    const float* w_msg1  = (const float*)d_in[6];
    const float* b_msg1  = (const float*)d_in[7];
    const float* w_msg2  = (const float*)d_in[8];
    const float* b_msg2  = (const float*)d_in[9];
    const float* w_out1  = (const float*)d_in[10];
    const float* b_out1  = (const float*)d_in[11];
    const float* w_out2  = (const float*)d_in[12];
    const float* b_out2  = (const float*)d_in[13];
    const float* w_out3  = (const float*)d_in[14];
    const float* b_out3  = (const float*)d_in[15];
    float* out = (float*)d_out;

    // workspace (f16 elems): u, v, agg (11700*256 each); frag-order W2, Wout1, Wout2
    f16* u       = (f16*)d_ws;
    f16* v       = u       + NROWS * HID;
    f16* aggw    = v       + NROWS * HID;
    f16* w2frag  = aggw    + NROWS * HID;
    f16* w1frag  = w2frag  + W2F_ELEMS;
    f16* w2ofrag = w1frag  + W1F_ELEMS;   // total ~18.4 MB

    hipLaunchKernelGGL(k1_prep, dim3(UVB + 32 + 36 + 32), dim3(256), 0, stream,
                       inputs, w_msg1, b_msg1, w_msg2, w_out1, w_out2,
                       u, v, w2frag, w1frag, w2ofrag);
    hipLaunchKernelGGL(k2_msg, dim3(NB * NA * TB3), dim3(256), 0, stream,
                       u, v, w2frag, mu, logvar, eps, b_msg2, aggw);
    hipLaunchKernelGGL(k3_out, dim3((NROWS + 15) / 16), dim3(256), 0, stream,
                       aggw, inputs, w1frag, w2ofrag, b_out1, b_out2, w_out3, b_out3, out);
}